// Round 2
// baseline (371.490 us; speedup 1.0000x reference)
//
#include <hip/hip_runtime.h>
#include <hip/hip_bf16.h>

typedef __attribute__((ext_vector_type(4))) float f32x4;
typedef __attribute__((ext_vector_type(8))) short s16x8;
typedef unsigned short u16;

__device__ __forceinline__ u16 f2bf(float f) {
    union { float f; unsigned int u; } a; a.f = f;
    unsigned int u = a.u;
    unsigned int lsb = (u >> 16) & 1u;
    u += 0x7fffu + lsb;               // round-to-nearest-even
    return (u16)(u >> 16);
}

// async global->LDS, 16B per lane; LDS dest = wave-uniform base + lane*16 (HW adds lane offset)
__device__ __forceinline__ void gll16(const u16* g, u16* l) {
    __builtin_amdgcn_global_load_lds(
        (const __attribute__((address_space(1))) unsigned int*)g,
        (__attribute__((address_space(3))) unsigned int*)l, 16, 0, 0);
}

// ---------------- conversion kernels ----------------

__global__ void cvt_x_kernel(const float* __restrict__ x, u16* __restrict__ xb, int n4) {
    int i = blockIdx.x * 256 + threadIdx.x;
    if (i < n4) {
        float4 v = ((const float4*)x)[i];
        ushort4 o;
        o.x = f2bf(v.x); o.y = f2bf(v.y); o.z = f2bf(v.z); o.w = f2bf(v.w);
        ((ushort4*)xb)[i] = o;
    }
}

template<int KK, int NN>
__global__ void cvt_wT_kernel(const float* __restrict__ w, u16* __restrict__ wt) {
    int i = blockIdx.x * 256 + threadIdx.x;
    if (i < KK * NN) {
        int k = i / NN, n = i % NN;          // w is [KK][NN] row-major
        wt[n * KK + k] = f2bf(w[i]);         // wt is [NN][KK]
    }
}

// ---------------- GEMM mainloop (128x128 tile, BK=64, m97-style global_load_lds staging) ----
// LDS tiles are UNPADDED [128][64] u16 with XOR granule swizzle:
//   physical granule p = row*8 + (cg ^ (row&7)), cg = logical 16B-granule (d/8).
// Staging permutes the GLOBAL source address so the wave's contiguous 1KiB LDS write lands
// swizzled; ds_read_b128 frag reads then hit all 32 banks uniformly (8/bank, minimal).

template<int K>
__device__ __forceinline__ void gemm_tile(const u16* __restrict__ A, const u16* __restrict__ Bt,
                                          int m0, int n0, u16* As, u16* Bs, f32x4 (&acc)[4][4]) {
    const int tid  = threadIdx.x;
    const int lane = tid & 63, li = lane & 15, quad = lane >> 4;
    const int w = tid >> 6;
    const int wm = (w & 1) * 64, wn = (w >> 1) * 64;
    const int lr = lane >> 3;               // 0..7: row-within-8 this lane stages
    const int lc = (lane & 7) ^ lr;         // swizzled source granule

    for (int kt = 0; kt < K; kt += 64) {
#pragma unroll
        for (int j = 0; j < 4; ++j)
            gll16(&A[(m0 + w * 32 + j * 8 + lr) * K + kt + lc * 8], &As[(w * 256 + j * 64) * 8]);
#pragma unroll
        for (int j = 0; j < 4; ++j)
            gll16(&Bt[(n0 + w * 32 + j * 8 + lr) * K + kt + lc * 8], &Bs[(w * 256 + j * 64) * 8]);
        __syncthreads();
#pragma unroll
        for (int kc = 0; kc < 2; ++kc) {
            const int sw = ((quad + kc * 4) ^ (li & 7)) * 8;
            s16x8 af[4], bfr[4];
#pragma unroll
            for (int i = 0; i < 4; ++i)
                af[i] = *(const s16x8*)&As[(wm + i * 16 + li) * 64 + sw];
#pragma unroll
            for (int i = 0; i < 4; ++i)
                bfr[i] = *(const s16x8*)&Bs[(wn + i * 16 + li) * 64 + sw];
#pragma unroll
            for (int i = 0; i < 4; ++i)
#pragma unroll
                for (int j = 0; j < 4; ++j)
                    acc[i][j] = __builtin_amdgcn_mfma_f32_16x16x32_bf16(af[i], bfr[j], acc[i][j], 0, 0, 0);
        }
        __syncthreads();
    }
}

// ---------------- GEMM1: qkv = x @ W_qkv + b_qkv -> Q,K natural [b,h,t,64]; V transposed-blocked ----
// Vt layout: [b,h][s>>5][d][s&31]  (element (s,d) at bh + (s>>5)*2048 + d*32 + (s&31))

__global__ __launch_bounds__(256) void gemm_qkv_kernel(const u16* __restrict__ xb,
                                                       const u16* __restrict__ WqkvT,
                                                       const float* __restrict__ b_qkv,
                                                       u16* __restrict__ Qb, u16* __restrict__ Kb,
                                                       u16* __restrict__ Vtb) {
    __shared__ __align__(16) u16 As[128 * 64];
    __shared__ __align__(16) u16 Bs[128 * 64];
    f32x4 acc[4][4];
#pragma unroll
    for (int i = 0; i < 4; ++i)
#pragma unroll
        for (int j = 0; j < 4; ++j) acc[i][j] = {0.f, 0.f, 0.f, 0.f};
    const int m0 = blockIdx.y * 128, n0 = blockIdx.x * 128;
    gemm_tile<512>(xb, WqkvT, m0, n0, As, Bs, acc);

    const int tid = threadIdx.x, lane = tid & 63, li = lane & 15, quad = lane >> 4, wave = tid >> 6;
    const int wm = (wave & 1) * 64, wn = (wave >> 1) * 64;
#pragma unroll
    for (int j = 0; j < 4; ++j) {
        int col = n0 + wn + j * 16 + li;          // 0..1535
        float bias = b_qkv[col];
        int which = col >> 9, hh = (col >> 6) & 7, dd = col & 63;
#pragma unroll
        for (int i = 0; i < 4; ++i)
#pragma unroll
            for (int r = 0; r < 4; ++r) {
                int row = m0 + wm + i * 16 + quad * 4 + r;   // 0..32767
                int bb = row >> 8, tt = row & 255;
                int bh = (bb * 8 + hh) << 14;
                u16 val = f2bf(acc[i][j][r] + bias);
                if (which == 0)       Qb[bh + tt * 64 + dd] = val;
                else if (which == 1)  Kb[bh + tt * 64 + dd] = val;
                else                  Vtb[bh + (tt >> 5) * 2048 + dd * 32 + (tt & 31)] = val;
            }
    }
}

// ---------------- GEMM2: out = Yb @ W_out + b_out (fp32 out) ----------------

__global__ __launch_bounds__(256) void gemm_out_kernel(const u16* __restrict__ Yb,
                                                       const u16* __restrict__ WoutT,
                                                       const float* __restrict__ b_out,
                                                       float* __restrict__ out) {
    __shared__ __align__(16) u16 As[128 * 64];
    __shared__ __align__(16) u16 Bs[128 * 64];
    f32x4 acc[4][4];
#pragma unroll
    for (int i = 0; i < 4; ++i)
#pragma unroll
        for (int j = 0; j < 4; ++j) acc[i][j] = {0.f, 0.f, 0.f, 0.f};
    const int m0 = blockIdx.y * 128, n0 = blockIdx.x * 128;
    gemm_tile<512>(Yb, WoutT, m0, n0, As, Bs, acc);

    const int tid = threadIdx.x, lane = tid & 63, li = lane & 15, quad = lane >> 4, wave = tid >> 6;
    const int wm = (wave & 1) * 64, wn = (wave >> 1) * 64;
#pragma unroll
    for (int j = 0; j < 4; ++j) {
        int col = n0 + wn + j * 16 + li;
        float bias = b_out[col];
#pragma unroll
        for (int i = 0; i < 4; ++i)
#pragma unroll
            for (int r = 0; r < 4; ++r) {
                int row = m0 + wm + i * 16 + quad * 4 + r;
                out[row * 512 + col] = acc[i][j][r] + bias;
            }
    }
}

// ---------------- attention: barrier-free; Q/K/Vt frags loaded DIRECT from global ----------------
// One block per (b, h, 64 q-rows); wave owns 16 q-rows; full 16x256 score row in 16 accumulators.
// Only LDS use: per-wave P C-layout -> A-layout round-trip (no __syncthreads anywhere).

__global__ __launch_bounds__(256) void attn_kernel(const u16* __restrict__ Qb,
                                                   const u16* __restrict__ Kb,
                                                   const u16* __restrict__ Vtb,
                                                   u16* __restrict__ Yb) {
    __shared__ __align__(16) u16 pl[4 * 16 * 264];   // 4 waves x 16 t x 264 s (pad)

    const int tid = threadIdx.x, wave = tid >> 6, lane = tid & 63, li = lane & 15, quad = lane >> 4;
    const int b = blockIdx.z, h = blockIdx.y, qt = blockIdx.x;
    const int bh = (b * 8 + h) << 14;          // per-head 16384 elements
    const int qrb = qt * 64 + wave * 16;
    const int nst = (qrb >> 4) + 1;            // valid 16-wide s-tiles for this wave

    // Q fragments (A-operand): A[m=li][k=quad*8+j], two 32-k chunks
    s16x8 qf0 = *(const s16x8*)&Qb[bh + (qrb + li) * 64 + quad * 8];
    s16x8 qf1 = *(const s16x8*)&Qb[bh + (qrb + li) * 64 + 32 + quad * 8];

    f32x4 sacc[16];
#pragma unroll
    for (int st = 0; st < 16; ++st) sacc[st] = {0.f, 0.f, 0.f, 0.f};

    // ---- S = Q K^T : direct global K-frag loads (lane li = s-row, contiguous d = coalesced),
    //      grouped 4 tiles ahead for memory-level parallelism ----
#pragma unroll
    for (int g = 0; g < 4; ++g) {
        if (g * 4 < nst) {
            s16x8 kf[4][2];
#pragma unroll
            for (int t = 0; t < 4; ++t) {
                if (g * 4 + t < nst) {
                    const u16* kp = &Kb[bh + ((g * 4 + t) * 16 + li) * 64 + quad * 8];
                    kf[t][0] = *(const s16x8*)kp;
                    kf[t][1] = *(const s16x8*)(kp + 32);
                }
            }
#pragma unroll
            for (int t = 0; t < 4; ++t) {
                if (g * 4 + t < nst) {
                    sacc[g * 4 + t] = __builtin_amdgcn_mfma_f32_16x16x32_bf16(qf0, kf[t][0], sacc[g * 4 + t], 0, 0, 0);
                    sacc[g * 4 + t] = __builtin_amdgcn_mfma_f32_16x16x32_bf16(qf1, kf[t][1], sacc[g * 4 + t], 0, 0, 0);
                }
            }
        }
    }

    // ---- softmax over the full row (scale 1/8, causal mask) ----
    float mx[4] = {-3e38f, -3e38f, -3e38f, -3e38f};
#pragma unroll
    for (int st = 0; st < 16; ++st) {
        if (st < nst) {
            int sg = st * 16 + li;
#pragma unroll
            for (int r = 0; r < 4; ++r) {
                int tg = qrb + quad * 4 + r;
                float v = (sg <= tg) ? sacc[st][r] * 0.125f : -3e38f;
                sacc[st][r] = v;
                mx[r] = fmaxf(mx[r], v);
            }
        }
    }
#pragma unroll
    for (int d = 1; d < 16; d <<= 1)
#pragma unroll
        for (int r = 0; r < 4; ++r) mx[r] = fmaxf(mx[r], __shfl_xor(mx[r], d, 64));

    float l[4] = {0.f, 0.f, 0.f, 0.f};
    const int ns32 = (nst + 1) >> 1;           // 32-wide PV chunks
    const int nstw = ns32 * 2;                 // tiles written to pl (zero-pad odd tail)
#pragma unroll
    for (int st = 0; st < 16; ++st) {
        if (st < nstw) {
#pragma unroll
            for (int r = 0; r < 4; ++r) {
                float e = (st < nst) ? __expf(sacc[st][r] - mx[r]) : 0.f;
                l[r] += e;
                pl[wave * 4224 + (quad * 4 + r) * 264 + st * 16 + li] = f2bf(e);
            }
        }
    }
#pragma unroll
    for (int d = 1; d < 16; d <<= 1)
#pragma unroll
        for (int r = 0; r < 4; ++r) l[r] += __shfl_xor(l[r], d, 64);

    // ---- O = P V : P from wave-private LDS (A-operand), V^T-frag direct from blocked global ----
    f32x4 oacc[4];
#pragma unroll
    for (int dt = 0; dt < 4; ++dt) oacc[dt] = {0.f, 0.f, 0.f, 0.f};

#pragma unroll
    for (int c = 0; c < 8; ++c) {
        if (c < ns32) {
            s16x8 pf = *(const s16x8*)&pl[wave * 4224 + li * 264 + c * 32 + quad * 8];
            s16x8 vf[4];
#pragma unroll
            for (int dt = 0; dt < 4; ++dt)
                vf[dt] = *(const s16x8*)&Vtb[bh + c * 2048 + (dt * 16 + li) * 32 + quad * 8];
#pragma unroll
            for (int dt = 0; dt < 4; ++dt)
                oacc[dt] = __builtin_amdgcn_mfma_f32_16x16x32_bf16(pf, vf[dt], oacc[dt], 0, 0, 0);
        }
    }

    // ---- epilogue: Yb[b,t, h*64+d] = O / l ----
    float inv[4];
#pragma unroll
    for (int r = 0; r < 4; ++r) inv[r] = 1.0f / l[r];
#pragma unroll
    for (int dt = 0; dt < 4; ++dt)
#pragma unroll
        for (int r = 0; r < 4; ++r) {
            int tg = qrb + quad * 4 + r;
            Yb[(b * 256 + tg) * 512 + h * 64 + dt * 16 + li] = f2bf(oacc[dt][r] * inv[r]);
        }
}

// ---------------- launch ----------------

extern "C" void kernel_launch(void* const* d_in, const int* in_sizes, int n_in,
                              void* d_out, int out_size, void* d_ws, size_t ws_size,
                              hipStream_t stream) {
    const float* x     = (const float*)d_in[0];
    const float* W_qkv = (const float*)d_in[1];
    const float* b_qkv = (const float*)d_in[2];
    const float* W_out = (const float*)d_in[3];
    const float* b_out = (const float*)d_in[4];
    float* out = (float*)d_out;

    char* ws = (char*)d_ws;
    u16* Qb    = (u16*)(ws);                       //  33,554,432
    u16* Kb    = (u16*)(ws + 33554432);            //  33,554,432
    u16* Vtb   = (u16*)(ws + 67108864);            //  33,554,432 (transposed-blocked)
    u16* WqkvT = (u16*)(ws + 100663296);           //   1,572,864
    u16* WoutT = (u16*)(ws + 102236160);           //     524,288
    u16* xb    = (u16*)(ws + 102760448);           //  33,554,432 (reused as Yb after GEMM1)
    u16* Yb    = xb;
    if (ws_size < (size_t)136314880) return;       // need ~130 MB scratch

    cvt_x_kernel<<<16384, 256, 0, stream>>>(x, xb, 4194304);
    cvt_wT_kernel<512, 1536><<<3072, 256, 0, stream>>>(W_qkv, WqkvT);
    cvt_wT_kernel<512, 512><<<1024, 256, 0, stream>>>(W_out, WoutT);
    gemm_qkv_kernel<<<dim3(12, 256), 256, 0, stream>>>(xb, WqkvT, b_qkv, Qb, Kb, Vtb);
    attn_kernel<<<dim3(4, 8, 128), 256, 0, stream>>>(Qb, Kb, Vtb, Yb);
    gemm_out_kernel<<<dim3(4, 256), 256, 0, stream>>>(Yb, WoutT, b_out, out);
}

// Round 3
// 358.123 us; speedup vs baseline: 1.0373x; 1.0373x over previous
//
#include <hip/hip_runtime.h>
#include <hip/hip_bf16.h>

typedef __attribute__((ext_vector_type(4))) float f32x4;
typedef __attribute__((ext_vector_type(8))) short s16x8;
typedef unsigned short u16;

__device__ __forceinline__ u16 f2bf(float f) {
    union { float f; unsigned int u; } a; a.f = f;
    unsigned int u = a.u;
    unsigned int lsb = (u >> 16) & 1u;
    u += 0x7fffu + lsb;               // round-to-nearest-even
    return (u16)(u >> 16);
}

// async global->LDS, 16B per lane; LDS dest = wave-uniform base + lane*16
__device__ __forceinline__ void gll16(const u16* g, u16* l) {
    __builtin_amdgcn_global_load_lds(
        (const __attribute__((address_space(1))) unsigned int*)g,
        (__attribute__((address_space(3))) unsigned int*)l, 16, 0, 0);
}

// ---------------- conversion kernels ----------------

__global__ void cvt_x_kernel(const float* __restrict__ x, u16* __restrict__ xb, int n4) {
    int i = blockIdx.x * 256 + threadIdx.x;
    if (i < n4) {
        float4 v = ((const float4*)x)[i];
        ushort4 o;
        o.x = f2bf(v.x); o.y = f2bf(v.y); o.z = f2bf(v.z); o.w = f2bf(v.w);
        ((ushort4*)xb)[i] = o;
    }
}

// W [KK][NN] fp32 -> wt [NN][KK] bf16. Coalesced fp32 reads (lanes = adjacent n),
// ushort8 writes (16B per lane, lane-stride KK*2B).
template<int KK, int NN>
__global__ void cvt_wT_kernel(const float* __restrict__ w, u16* __restrict__ wt) {
    int id = blockIdx.x * 256 + threadIdx.x;          // over NN * KK/8
    if (id < NN * (KK / 8)) {
        int n = id % NN, kg = id / NN;
        union { u16 h[8]; int4 v; } o;
#pragma unroll
        for (int e = 0; e < 8; ++e) o.h[e] = f2bf(w[(kg * 8 + e) * NN + n]);
        *(int4*)&wt[n * KK + kg * 8] = o.v;
    }
}

// ---------------- GEMM mainloop (128x128 tile, BK=64, global_load_lds staging) ----
// LDS tiles UNPADDED [128][64] u16, XOR granule swizzles:
//   As: phys granule p of row R holds source granule p ^ (R&7)
//   Bs: phys granule p of row R holds source granule p ^ ((R>>2)&7)
// Frag reads (A rows wm+i*16+li; B rows wn+li*4+j) then share ONE swizzle expr
//   sw = ((quad + kc*4) ^ (li&7)) * 8  -> uniform 8-accesses/bank (minimum), 0 conflicts.
// B-column PERMUTATION: B-frag lane li <- matrix col wn+li*4+j, so acc[i][0..3][r]
// hold 4 contiguous output columns -> vectorized coalesced epilogue stores.

template<int K>
__device__ __forceinline__ void gemm_tile(const u16* __restrict__ A, const u16* __restrict__ Bt,
                                          int m0, int n0, u16* As, u16* Bs, f32x4 (&acc)[4][4]) {
    const int tid  = threadIdx.x;
    const int lane = tid & 63, li = lane & 15, quad = lane >> 4;
    const int w = tid >> 6;
    const int wm = (w & 1) * 64, wn = (w >> 1) * 64;
    const int lr  = lane >> 3;                 // row-within-8 this lane stages
    const int lcA = (lane & 7) ^ lr;           // A source granule
    const int lt  = lane >> 5;

    for (int kt = 0; kt < K; kt += 64) {
#pragma unroll
        for (int j = 0; j < 4; ++j)
            gll16(&A[(m0 + w * 32 + j * 8 + lr) * K + kt + lcA * 8], &As[(w * 256 + j * 64) * 8]);
#pragma unroll
        for (int j = 0; j < 4; ++j) {
            int lcB = (lane & 7) ^ ((j * 2 + lt) & 7);
            gll16(&Bt[(n0 + w * 32 + j * 8 + lr) * K + kt + lcB * 8], &Bs[(w * 256 + j * 64) * 8]);
        }
        __syncthreads();
#pragma unroll
        for (int kc = 0; kc < 2; ++kc) {
            const int sw = ((quad + kc * 4) ^ (li & 7)) * 8;
            s16x8 af[4], bfr[4];
#pragma unroll
            for (int i = 0; i < 4; ++i)
                af[i] = *(const s16x8*)&As[(wm + i * 16 + li) * 64 + sw];
#pragma unroll
            for (int j = 0; j < 4; ++j)
                bfr[j] = *(const s16x8*)&Bs[(wn + li * 4 + j) * 64 + sw];
#pragma unroll
            for (int i = 0; i < 4; ++i)
#pragma unroll
                for (int j = 0; j < 4; ++j)
                    acc[i][j] = __builtin_amdgcn_mfma_f32_16x16x32_bf16(af[i], bfr[j], acc[i][j], 0, 0, 0);
        }
        __syncthreads();
    }
}

// ---------------- GEMM1: qkv = x @ W_qkv + b_qkv -> Q,K natural [b,h,t,64]; V blocked-T ----
// Vt layout: element (s,d) at bh + (s>>5)*2048 + d*32 + (s&31)
// Grid 3072 1-D, XCD-swizzled: per-XCD contiguous m-tiles (A fetched once per tile).

__global__ __launch_bounds__(256) void gemm_qkv_kernel(const u16* __restrict__ xb,
                                                       const u16* __restrict__ WqkvT,
                                                       const float* __restrict__ b_qkv,
                                                       u16* __restrict__ Qb, u16* __restrict__ Kb,
                                                       u16* __restrict__ Vtb) {
    __shared__ __align__(16) u16 As[128 * 64];
    __shared__ __align__(16) u16 Bs[128 * 64];
    f32x4 acc[4][4];
#pragma unroll
    for (int i = 0; i < 4; ++i)
#pragma unroll
        for (int j = 0; j < 4; ++j) acc[i][j] = {0.f, 0.f, 0.f, 0.f};

    const int id = blockIdx.x, xcd = id & 7, slot = id >> 3;
    const int mt = xcd * 32 + slot / 12, nt = slot - (slot / 12) * 12;
    const int m0 = mt * 128, n0 = nt * 128;
    gemm_tile<512>(xb, WqkvT, m0, n0, As, Bs, acc);

    const int tid = threadIdx.x, lane = tid & 63, li = lane & 15, quad = lane >> 4, wave = tid >> 6;
    const int wm = (wave & 1) * 64, wn = (wave >> 1) * 64;
    const int c0 = n0 + wn;                       // wave's 64-col slice: one dest, one head
    const int which = c0 >> 9, hh = (c0 >> 6) & 7;
    float4 b4 = *(const float4*)&b_qkv[c0 + li * 4];

#pragma unroll
    for (int i = 0; i < 4; ++i)
#pragma unroll
        for (int r = 0; r < 4; ++r) {
            int row = m0 + wm + i * 16 + quad * 4 + r;
            int bb = row >> 8, tt = row & 255;
            int bh = (bb * 8 + hh) << 14;
            u16 v0 = f2bf(acc[i][0][r] + b4.x), v1 = f2bf(acc[i][1][r] + b4.y);
            u16 v2 = f2bf(acc[i][2][r] + b4.z), v3 = f2bf(acc[i][3][r] + b4.w);
            if (which == 0) {
                *(ushort4*)&Qb[bh + tt * 64 + li * 4] = (ushort4){v0, v1, v2, v3};
            } else if (which == 1) {
                *(ushort4*)&Kb[bh + tt * 64 + li * 4] = (ushort4){v0, v1, v2, v3};
            } else {
                int vb = bh + (tt >> 5) * 2048 + (tt & 31);
                Vtb[vb + (li * 4 + 0) * 32] = v0;
                Vtb[vb + (li * 4 + 1) * 32] = v1;
                Vtb[vb + (li * 4 + 2) * 32] = v2;
                Vtb[vb + (li * 4 + 3) * 32] = v3;
            }
        }
}

// ---------------- GEMM2: out = Yb @ W_out + b_out (fp32 out, float4 stores) ----------------

__global__ __launch_bounds__(256) void gemm_out_kernel(const u16* __restrict__ Yb,
                                                       const u16* __restrict__ WoutT,
                                                       const float* __restrict__ b_out,
                                                       float* __restrict__ out) {
    __shared__ __align__(16) u16 As[128 * 64];
    __shared__ __align__(16) u16 Bs[128 * 64];
    f32x4 acc[4][4];
#pragma unroll
    for (int i = 0; i < 4; ++i)
#pragma unroll
        for (int j = 0; j < 4; ++j) acc[i][j] = {0.f, 0.f, 0.f, 0.f};

    const int id = blockIdx.x, xcd = id & 7, slot = id >> 3;
    const int mt = xcd * 32 + (slot >> 2), nt = slot & 3;
    const int m0 = mt * 128, n0 = nt * 128;
    gemm_tile<512>(Yb, WoutT, m0, n0, As, Bs, acc);

    const int tid = threadIdx.x, lane = tid & 63, li = lane & 15, quad = lane >> 4, wave = tid >> 6;
    const int wm = (wave & 1) * 64, wn = (wave >> 1) * 64;
    const int c0 = n0 + wn;
    float4 b4 = *(const float4*)&b_out[c0 + li * 4];

#pragma unroll
    for (int i = 0; i < 4; ++i)
#pragma unroll
        for (int r = 0; r < 4; ++r) {
            int row = m0 + wm + i * 16 + quad * 4 + r;
            float4 o;
            o.x = acc[i][0][r] + b4.x; o.y = acc[i][1][r] + b4.y;
            o.z = acc[i][2][r] + b4.z; o.w = acc[i][3][r] + b4.w;
            *(float4*)&out[row * 512 + c0 + li * 4] = o;
        }
}

// ---------------- attention: barrier-free; direct global frag loads; B-permuted PV ----------------
// Grid 4096 1-D, XCD-swizzled so all 4 q-tiles of one (b,h) share an XCD (K/V L2-local).

__global__ __launch_bounds__(256) void attn_kernel(const u16* __restrict__ Qb,
                                                   const u16* __restrict__ Kb,
                                                   const u16* __restrict__ Vtb,
                                                   u16* __restrict__ Yb) {
    __shared__ __align__(16) u16 pl[4 * 16 * 264];   // 4 waves x 16 t x 264 s (pad)

    const int tid = threadIdx.x, wave = tid >> 6, lane = tid & 63, li = lane & 15, quad = lane >> 4;
    const int id = blockIdx.x, xcd = id & 7, slot = id >> 3;
    const int bhid = xcd * 128 + (slot >> 2), qt = slot & 3;
    const int b = bhid >> 3, h = bhid & 7;
    const int bh = bhid << 14;
    const int qrb = qt * 64 + wave * 16;
    const int nst = (qrb >> 4) + 1;            // valid 16-wide s-tiles for this wave

    // Q fragments (A-operand): A[m=li][k=quad*8+j]
    s16x8 qf0 = *(const s16x8*)&Qb[bh + (qrb + li) * 64 + quad * 8];
    s16x8 qf1 = *(const s16x8*)&Qb[bh + (qrb + li) * 64 + 32 + quad * 8];

    f32x4 sacc[16];
#pragma unroll
    for (int st = 0; st < 16; ++st) sacc[st] = {0.f, 0.f, 0.f, 0.f};

    // ---- S = Q K^T : direct global K-frag loads, grouped 4 tiles for MLP ----
#pragma unroll
    for (int g = 0; g < 4; ++g) {
        if (g * 4 < nst) {
            s16x8 kf[4][2];
#pragma unroll
            for (int t = 0; t < 4; ++t) {
                if (g * 4 + t < nst) {
                    const u16* kp = &Kb[bh + ((g * 4 + t) * 16 + li) * 64 + quad * 8];
                    kf[t][0] = *(const s16x8*)kp;
                    kf[t][1] = *(const s16x8*)(kp + 32);
                }
            }
#pragma unroll
            for (int t = 0; t < 4; ++t) {
                if (g * 4 + t < nst) {
                    sacc[g * 4 + t] = __builtin_amdgcn_mfma_f32_16x16x32_bf16(qf0, kf[t][0], sacc[g * 4 + t], 0, 0, 0);
                    sacc[g * 4 + t] = __builtin_amdgcn_mfma_f32_16x16x32_bf16(qf1, kf[t][1], sacc[g * 4 + t], 0, 0, 0);
                }
            }
        }
    }

    // ---- softmax (scale 1/8, causal) ----
    float mx[4] = {-3e38f, -3e38f, -3e38f, -3e38f};
#pragma unroll
    for (int st = 0; st < 16; ++st) {
        if (st < nst) {
            int sg = st * 16 + li;
#pragma unroll
            for (int r = 0; r < 4; ++r) {
                int tg = qrb + quad * 4 + r;
                float v = (sg <= tg) ? sacc[st][r] * 0.125f : -3e38f;
                sacc[st][r] = v;
                mx[r] = fmaxf(mx[r], v);
            }
        }
    }
#pragma unroll
    for (int d = 1; d < 16; d <<= 1)
#pragma unroll
        for (int r = 0; r < 4; ++r) mx[r] = fmaxf(mx[r], __shfl_xor(mx[r], d, 64));

    float l[4] = {0.f, 0.f, 0.f, 0.f};
    const int ns32 = (nst + 1) >> 1;           // 32-wide PV chunks
    const int nstw = ns32 * 2;                 // tiles written to pl (zero-pad odd tail)
#pragma unroll
    for (int st = 0; st < 16; ++st) {
        if (st < nstw) {
#pragma unroll
            for (int r = 0; r < 4; ++r) {
                float e = (st < nst) ? __expf(sacc[st][r] - mx[r]) : 0.f;
                l[r] += e;
                pl[wave * 4224 + (quad * 4 + r) * 264 + st * 16 + li] = f2bf(e);
            }
        }
    }
#pragma unroll
    for (int d = 1; d < 16; d <<= 1)
#pragma unroll
        for (int r = 0; r < 4; ++r) l[r] += __shfl_xor(l[r], d, 64);

    // ---- O = P V : B-permuted (lane li <- d col li*4+dt) ----
    f32x4 oacc[4];
#pragma unroll
    for (int dt = 0; dt < 4; ++dt) oacc[dt] = {0.f, 0.f, 0.f, 0.f};

#pragma unroll
    for (int c = 0; c < 8; ++c) {
        if (c < ns32) {
            s16x8 pf = *(const s16x8*)&pl[wave * 4224 + li * 264 + c * 32 + quad * 8];
            s16x8 vf[4];
#pragma unroll
            for (int dt = 0; dt < 4; ++dt)
                vf[dt] = *(const s16x8*)&Vtb[bh + c * 2048 + (li * 4 + dt) * 32 + quad * 8];
#pragma unroll
            for (int dt = 0; dt < 4; ++dt)
                oacc[dt] = __builtin_amdgcn_mfma_f32_16x16x32_bf16(pf, vf[dt], oacc[dt], 0, 0, 0);
        }
    }

    // ---- epilogue: Yb[b,t, h*64 + li*4 .. +3] = O / l  (ushort4 coalesced) ----
    float inv[4];
#pragma unroll
    for (int r = 0; r < 4; ++r) inv[r] = 1.0f / l[r];
#pragma unroll
    for (int r = 0; r < 4; ++r) {
        int tg = qrb + quad * 4 + r;
        ushort4 o;
        o.x = f2bf(oacc[0][r] * inv[r]); o.y = f2bf(oacc[1][r] * inv[r]);
        o.z = f2bf(oacc[2][r] * inv[r]); o.w = f2bf(oacc[3][r] * inv[r]);
        *(ushort4*)&Yb[(b * 256 + tg) * 512 + h * 64 + li * 4] = o;
    }
}

// ---------------- launch ----------------

extern "C" void kernel_launch(void* const* d_in, const int* in_sizes, int n_in,
                              void* d_out, int out_size, void* d_ws, size_t ws_size,
                              hipStream_t stream) {
    const float* x     = (const float*)d_in[0];
    const float* W_qkv = (const float*)d_in[1];
    const float* b_qkv = (const float*)d_in[2];
    const float* W_out = (const float*)d_in[3];
    const float* b_out = (const float*)d_in[4];
    float* out = (float*)d_out;

    char* ws = (char*)d_ws;
    u16* Qb    = (u16*)(ws);                       //  33,554,432
    u16* Kb    = (u16*)(ws + 33554432);            //  33,554,432
    u16* Vtb   = (u16*)(ws + 67108864);            //  33,554,432 (transposed-blocked)
    u16* WqkvT = (u16*)(ws + 100663296);           //   1,572,864
    u16* WoutT = (u16*)(ws + 102236160);           //     524,288
    u16* xb    = (u16*)(ws + 102760448);           //  33,554,432 (reused as Yb after GEMM1)
    u16* Yb    = xb;
    if (ws_size < (size_t)136314880) return;       // need ~130 MB scratch

    cvt_x_kernel<<<16384, 256, 0, stream>>>(x, xb, 4194304);
    cvt_wT_kernel<512, 1536><<<384, 256, 0, stream>>>(W_qkv, WqkvT);
    cvt_wT_kernel<512, 512><<<128, 256, 0, stream>>>(W_out, WoutT);
    gemm_qkv_kernel<<<3072, 256, 0, stream>>>(xb, WqkvT, b_qkv, Qb, Kb, Vtb);
    attn_kernel<<<4096, 256, 0, stream>>>(Qb, Kb, Vtb, Yb);
    gemm_out_kernel<<<1024, 256, 0, stream>>>(Yb, WoutT, b_out, out);
}

// Round 4
// 310.768 us; speedup vs baseline: 1.1954x; 1.1524x over previous
//
#include <hip/hip_runtime.h>
#include <hip/hip_bf16.h>

typedef __attribute__((ext_vector_type(4))) float f32x4;
typedef __attribute__((ext_vector_type(8))) short s16x8;
typedef unsigned short u16;

__device__ __forceinline__ u16 f2bf(float f) {
    union { float f; unsigned int u; } a; a.f = f;
    unsigned int u = a.u;
    unsigned int lsb = (u >> 16) & 1u;
    u += 0x7fffu + lsb;               // round-to-nearest-even
    return (u16)(u >> 16);
}

// async global->LDS, 16B per lane; LDS dest = wave-uniform base + lane*16
__device__ __forceinline__ void gll16(const u16* g, u16* l) {
    __builtin_amdgcn_global_load_lds(
        (const __attribute__((address_space(1))) unsigned int*)g,
        (__attribute__((address_space(3))) unsigned int*)l, 16, 0, 0);
}

// ---------------- conversion kernels ----------------

__global__ void cvt_x_kernel(const float* __restrict__ x, u16* __restrict__ xb, int n4) {
    int i = blockIdx.x * 256 + threadIdx.x;
    if (i < n4) {
        float4 v = ((const float4*)x)[i];
        ushort4 o;
        o.x = f2bf(v.x); o.y = f2bf(v.y); o.z = f2bf(v.z); o.w = f2bf(v.w);
        ((ushort4*)xb)[i] = o;
    }
}

// W [KK][NN] fp32 -> wt [NN][KK] bf16. Coalesced fp32 reads, ushort8 writes.
template<int KK, int NN>
__global__ void cvt_wT_kernel(const float* __restrict__ w, u16* __restrict__ wt) {
    int id = blockIdx.x * 256 + threadIdx.x;          // over NN * KK/8
    if (id < NN * (KK / 8)) {
        int n = id % NN, kg = id / NN;
        union { u16 h[8]; int4 v; } o;
#pragma unroll
        for (int e = 0; e < 8; ++e) o.h[e] = f2bf(w[(kg * 8 + e) * NN + n]);
        *(int4*)&wt[n * KK + kg * 8] = o.v;
    }
}

// ---------------- GEMM mainloop (128x128 tile, BK=64, global_load_lds staging) ----
// LDS tiles UNPADDED [128][64] u16, XOR granule swizzles (0 bank conflicts, verified R2).
// B-column PERMUTATION: B-frag lane li <- matrix col wn+li*4+j -> vectorized epilogue.

template<int K>
__device__ __forceinline__ void gemm_tile(const u16* __restrict__ A, const u16* __restrict__ Bt,
                                          int m0, int n0, u16* As, u16* Bs, f32x4 (&acc)[4][4]) {
    const int tid  = threadIdx.x;
    const int lane = tid & 63, li = lane & 15, quad = lane >> 4;
    const int w = tid >> 6;
    const int wm = (w & 1) * 64, wn = (w >> 1) * 64;
    const int lr  = lane >> 3;                 // row-within-8 this lane stages
    const int lcA = (lane & 7) ^ lr;           // A source granule
    const int lt  = lane >> 5;

    for (int kt = 0; kt < K; kt += 64) {
#pragma unroll
        for (int j = 0; j < 4; ++j)
            gll16(&A[(m0 + w * 32 + j * 8 + lr) * K + kt + lcA * 8], &As[(w * 256 + j * 64) * 8]);
#pragma unroll
        for (int j = 0; j < 4; ++j) {
            int lcB = (lane & 7) ^ ((j * 2 + lt) & 7);
            gll16(&Bt[(n0 + w * 32 + j * 8 + lr) * K + kt + lcB * 8], &Bs[(w * 256 + j * 64) * 8]);
        }
        __syncthreads();
#pragma unroll
        for (int kc = 0; kc < 2; ++kc) {
            const int sw = ((quad + kc * 4) ^ (li & 7)) * 8;
            s16x8 af[4], bfr[4];
#pragma unroll
            for (int i = 0; i < 4; ++i)
                af[i] = *(const s16x8*)&As[(wm + i * 16 + li) * 64 + sw];
#pragma unroll
            for (int j = 0; j < 4; ++j)
                bfr[j] = *(const s16x8*)&Bs[(wn + li * 4 + j) * 64 + sw];
#pragma unroll
            for (int i = 0; i < 4; ++i)
#pragma unroll
                for (int j = 0; j < 4; ++j)
                    acc[i][j] = __builtin_amdgcn_mfma_f32_16x16x32_bf16(af[i], bfr[j], acc[i][j], 0, 0, 0);
        }
        __syncthreads();
    }
}

// ---------------- GEMM1: qkv = x @ W_qkv + b_qkv -> Q,K natural [b,h,t,64]; V blocked-T ----
// Vt layout: element (s,d) at bh + (s>>5)*2048 + d*32 + (s&31)

__global__ __launch_bounds__(256) void gemm_qkv_kernel(const u16* __restrict__ xb,
                                                       const u16* __restrict__ WqkvT,
                                                       const float* __restrict__ b_qkv,
                                                       u16* __restrict__ Qb, u16* __restrict__ Kb,
                                                       u16* __restrict__ Vtb) {
    __shared__ __align__(16) u16 As[128 * 64];
    __shared__ __align__(16) u16 Bs[128 * 64];
    f32x4 acc[4][4];
#pragma unroll
    for (int i = 0; i < 4; ++i)
#pragma unroll
        for (int j = 0; j < 4; ++j) acc[i][j] = {0.f, 0.f, 0.f, 0.f};

    const int id = blockIdx.x, xcd = id & 7, slot = id >> 3;
    const int mt = xcd * 32 + slot / 12, nt = slot - (slot / 12) * 12;
    const int m0 = mt * 128, n0 = nt * 128;
    gemm_tile<512>(xb, WqkvT, m0, n0, As, Bs, acc);

    const int tid = threadIdx.x, lane = tid & 63, li = lane & 15, quad = lane >> 4, wave = tid >> 6;
    const int wm = (wave & 1) * 64, wn = (wave >> 1) * 64;
    const int c0 = n0 + wn;                       // wave's 64-col slice: one dest, one head
    const int which = c0 >> 9, hh = (c0 >> 6) & 7;
    float4 b4 = *(const float4*)&b_qkv[c0 + li * 4];

#pragma unroll
    for (int i = 0; i < 4; ++i)
#pragma unroll
        for (int r = 0; r < 4; ++r) {
            int row = m0 + wm + i * 16 + quad * 4 + r;
            int bb = row >> 8, tt = row & 255;
            int bh = (bb * 8 + hh) << 14;
            u16 v0 = f2bf(acc[i][0][r] + b4.x), v1 = f2bf(acc[i][1][r] + b4.y);
            u16 v2 = f2bf(acc[i][2][r] + b4.z), v3 = f2bf(acc[i][3][r] + b4.w);
            if (which == 0) {
                *(ushort4*)&Qb[bh + tt * 64 + li * 4] = (ushort4){v0, v1, v2, v3};
            } else if (which == 1) {
                *(ushort4*)&Kb[bh + tt * 64 + li * 4] = (ushort4){v0, v1, v2, v3};
            } else {
                int vb = bh + (tt >> 5) * 2048 + (tt & 31);
                Vtb[vb + (li * 4 + 0) * 32] = v0;
                Vtb[vb + (li * 4 + 1) * 32] = v1;
                Vtb[vb + (li * 4 + 2) * 32] = v2;
                Vtb[vb + (li * 4 + 3) * 32] = v3;
            }
        }
}

// ---------------- GEMM2: out = Yb @ W_out + b_out (fp32 out, float4 stores) ----------------

__global__ __launch_bounds__(256) void gemm_out_kernel(const u16* __restrict__ Yb,
                                                       const u16* __restrict__ WoutT,
                                                       const float* __restrict__ b_out,
                                                       float* __restrict__ out) {
    __shared__ __align__(16) u16 As[128 * 64];
    __shared__ __align__(16) u16 Bs[128 * 64];
    f32x4 acc[4][4];
#pragma unroll
    for (int i = 0; i < 4; ++i)
#pragma unroll
        for (int j = 0; j < 4; ++j) acc[i][j] = {0.f, 0.f, 0.f, 0.f};

    const int id = blockIdx.x, xcd = id & 7, slot = id >> 3;
    const int mt = xcd * 32 + (slot >> 2), nt = slot & 3;
    const int m0 = mt * 128, n0 = nt * 128;
    gemm_tile<512>(Yb, WoutT, m0, n0, As, Bs, acc);

    const int tid = threadIdx.x, lane = tid & 63, li = lane & 15, quad = lane >> 4, wave = tid >> 6;
    const int wm = (wave & 1) * 64, wn = (wave >> 1) * 64;
    const int c0 = n0 + wn;
    float4 b4 = *(const float4*)&b_out[c0 + li * 4];

#pragma unroll
    for (int i = 0; i < 4; ++i)
#pragma unroll
        for (int r = 0; r < 4; ++r) {
            int row = m0 + wm + i * 16 + quad * 4 + r;
            float4 o;
            o.x = acc[i][0][r] + b4.x; o.y = acc[i][1][r] + b4.y;
            o.z = acc[i][2][r] + b4.z; o.w = acc[i][3][r] + b4.w;
            *(float4*)&out[row * 512 + c0 + li * 4] = o;
        }
}

// ---------------- attention v2: one block per (b,h); K staged once in LDS (swizzled) ----
// 4 waves; wave w processes q-tiles {w, 4+w, 8+w, 12+w} (balanced causal work).
// K-frag reads = conflict-free ds_read_b128. V-frags direct global, 1-chunk prefetch.
// P round-trip: per-wave ping-pong 16x40 buffers (16B-aligned reads, conflict-free writes).

__global__ __launch_bounds__(256, 2) void attn_kernel(const u16* __restrict__ Qb,
                                                      const u16* __restrict__ Kb,
                                                      const u16* __restrict__ Vtb,
                                                      u16* __restrict__ Yb) {
    __shared__ __align__(16) u16 Ks[256 * 64];        // granule-swizzled: phys g of row r = src g ^ (r&7)
    __shared__ __align__(16) u16 pl[4 * 2 * 16 * 40]; // per-wave ping-pong [t][40]

    const int tid = threadIdx.x, wave = tid >> 6, lane = tid & 63, li = lane & 15, quad = lane >> 4;
    const int bhid = blockIdx.x;
    const int b = bhid >> 3, h = bhid & 7;
    const int bh = bhid << 14;

    // Q frags for first tile (issue before staging so latency overlaps)
    s16x8 qf0 = *(const s16x8*)&Qb[bh + (wave * 16 + li) * 64 + quad * 8];
    s16x8 qf1 = *(const s16x8*)&Qb[bh + (wave * 16 + li) * 64 + 32 + quad * 8];

    // ---- stage K (32KB) via global_load_lds, swizzled ----
    {
        const int lr = lane >> 3;            // row-within-8 this lane stages
        const int sg = (lane & 7) ^ lr;      // source granule
#pragma unroll
        for (int j = 0; j < 8; ++j) {
            int blk = wave * 8 + j;          // 1KB block index
            gll16(&Kb[bh + (blk * 8 + lr) * 64 + sg * 8], &Ks[blk * 512]);
        }
    }
    __syncthreads();

    u16* plw = &pl[wave * 1280];

    for (int p = 0; p < 4; ++p) {
        const int qt = p * 4 + wave;
        const int qrb = qt * 16;
        const int nst = qt + 1;              // valid 16-wide s-tiles

        // ---- S = Q K^T from LDS, groups of 4 tiles ----
        f32x4 sacc[16];
#pragma unroll
        for (int st = 0; st < 16; ++st) sacc[st] = {0.f, 0.f, 0.f, 0.f};
        const int sw = li & 7;
#pragma unroll
        for (int g = 0; g < 4; ++g) {
            if (g * 4 < nst) {
                s16x8 kf[4][2];
#pragma unroll
                for (int t = 0; t < 4; ++t) {
                    if (g * 4 + t < nst) {
                        int rb = ((g * 4 + t) * 16 + li) * 64;
                        kf[t][0] = *(const s16x8*)&Ks[rb + ((quad    ) ^ sw) * 8];
                        kf[t][1] = *(const s16x8*)&Ks[rb + ((quad + 4) ^ sw) * 8];
                    }
                }
#pragma unroll
                for (int t = 0; t < 4; ++t) {
                    if (g * 4 + t < nst) {
                        sacc[g*4+t] = __builtin_amdgcn_mfma_f32_16x16x32_bf16(qf0, kf[t][0], sacc[g*4+t], 0, 0, 0);
                        sacc[g*4+t] = __builtin_amdgcn_mfma_f32_16x16x32_bf16(qf1, kf[t][1], sacc[g*4+t], 0, 0, 0);
                    }
                }
            }
        }

        // prefetch next tile's Q frags (overlaps softmax + PV below)
        s16x8 nqf0 = qf0, nqf1 = qf1;
        if (p < 3) {
            int nqrb = ((p + 1) * 4 + wave) * 16;
            nqf0 = *(const s16x8*)&Qb[bh + (nqrb + li) * 64 + quad * 8];
            nqf1 = *(const s16x8*)&Qb[bh + (nqrb + li) * 64 + 32 + quad * 8];
        }

        // ---- mask + scale + row-max ----
        float mx[4] = {-3e38f, -3e38f, -3e38f, -3e38f};
#pragma unroll
        for (int st = 0; st < 16; ++st) {
            if (st < nst) {
                int sg2 = st * 16 + li;
#pragma unroll
                for (int r = 0; r < 4; ++r) {
                    int tg = qrb + quad * 4 + r;
                    float v = (sg2 <= tg) ? sacc[st][r] * 0.125f : -3e38f;
                    sacc[st][r] = v;
                    mx[r] = fmaxf(mx[r], v);
                }
            }
        }
#pragma unroll
        for (int d = 1; d < 16; d <<= 1)
#pragma unroll
            for (int r = 0; r < 4; ++r) mx[r] = fmaxf(mx[r], __shfl_xor(mx[r], d, 64));

        // ---- PV pipelined: exp+write chunk, read pf, MFMA with prefetched V ----
        const int ns32 = (nst + 1) >> 1;
        float l[4] = {0.f, 0.f, 0.f, 0.f};
        f32x4 oacc[4];
#pragma unroll
        for (int dt = 0; dt < 4; ++dt) oacc[dt] = {0.f, 0.f, 0.f, 0.f};

        s16x8 vf[2][4];
#pragma unroll
        for (int dt = 0; dt < 4; ++dt)
            vf[0][dt] = *(const s16x8*)&Vtb[bh + (li * 4 + dt) * 32 + quad * 8];

#pragma unroll
        for (int c = 0; c < 8; ++c) {
            if (c < ns32) {
                if (c + 1 < ns32) {
#pragma unroll
                    for (int dt = 0; dt < 4; ++dt)
                        vf[(c + 1) & 1][dt] = *(const s16x8*)&Vtb[bh + (c + 1) * 2048 + (li * 4 + dt) * 32 + quad * 8];
                }
                u16* pb = plw + (c & 1) * 640;
#pragma unroll
                for (int half = 0; half < 2; ++half) {
                    int st = c * 2 + half;
#pragma unroll
                    for (int r = 0; r < 4; ++r) {
                        float e = (st < nst) ? __expf(sacc[st][r] - mx[r]) : 0.f;
                        l[r] += e;
                        pb[(quad * 4 + r) * 40 + half * 16 + li] = f2bf(e);
                    }
                }
                s16x8 pf = *(const s16x8*)&pb[li * 40 + quad * 8];
#pragma unroll
                for (int dt = 0; dt < 4; ++dt)
                    oacc[dt] = __builtin_amdgcn_mfma_f32_16x16x32_bf16(pf, vf[c & 1][dt], oacc[dt], 0, 0, 0);
            }
        }

#pragma unroll
        for (int d = 1; d < 16; d <<= 1)
#pragma unroll
            for (int r = 0; r < 4; ++r) l[r] += __shfl_xor(l[r], d, 64);

        // ---- epilogue: Yb[b,t, h*64 + li*4 .. +3] = O / l  (ushort4 coalesced) ----
#pragma unroll
        for (int r = 0; r < 4; ++r) {
            int tg = qrb + quad * 4 + r;
            float inv = 1.0f / l[r];
            ushort4 o;
            o.x = f2bf(oacc[0][r] * inv); o.y = f2bf(oacc[1][r] * inv);
            o.z = f2bf(oacc[2][r] * inv); o.w = f2bf(oacc[3][r] * inv);
            *(ushort4*)&Yb[(b * 256 + tg) * 512 + h * 64 + li * 4] = o;
        }

        qf0 = nqf0; qf1 = nqf1;
    }
}

// ---------------- launch ----------------

extern "C" void kernel_launch(void* const* d_in, const int* in_sizes, int n_in,
                              void* d_out, int out_size, void* d_ws, size_t ws_size,
                              hipStream_t stream) {
    const float* x     = (const float*)d_in[0];
    const float* W_qkv = (const float*)d_in[1];
    const float* b_qkv = (const float*)d_in[2];
    const float* W_out = (const float*)d_in[3];
    const float* b_out = (const float*)d_in[4];
    float* out = (float*)d_out;

    char* ws = (char*)d_ws;
    u16* Qb    = (u16*)(ws);                       //  33,554,432
    u16* Kb    = (u16*)(ws + 33554432);            //  33,554,432
    u16* Vtb   = (u16*)(ws + 67108864);            //  33,554,432 (transposed-blocked)
    u16* WqkvT = (u16*)(ws + 100663296);           //   1,572,864
    u16* WoutT = (u16*)(ws + 102236160);           //     524,288
    u16* xb    = (u16*)(ws + 102760448);           //  33,554,432 (reused as Yb after GEMM1)
    u16* Yb    = xb;
    if (ws_size < (size_t)136314880) return;       // need ~130 MB scratch

    cvt_x_kernel<<<16384, 256, 0, stream>>>(x, xb, 4194304);
    cvt_wT_kernel<512, 1536><<<384, 256, 0, stream>>>(W_qkv, WqkvT);
    cvt_wT_kernel<512, 512><<<128, 256, 0, stream>>>(W_out, WoutT);
    gemm_qkv_kernel<<<3072, 256, 0, stream>>>(xb, WqkvT, b_qkv, Qb, Kb, Vtb);
    attn_kernel<<<1024, 256, 0, stream>>>(Qb, Kb, Vtb, Yb);
    gemm_out_kernel<<<1024, 256, 0, stream>>>(Yb, WoutT, b_out, out);
}